// Round 1
// baseline (755.819 us; speedup 1.0000x reference)
//
#include <hip/hip_runtime.h>
#include <stdint.h>

#define T_ 10
#define B_ 4
#define C_ 384
#define N_ 384
#define H_ 12
#define CN_ 147456      // C_*N_
#define TBCN_ 5898240   // T_*B_*C_*N_
#define BCN_ 589824     // B_*C_*N_

// ---------------------------------------------------------------------------
// conv1: the 6 first-layer convs (fp32 GEMM, shared RHS x or y) + BN + LIF.
// Output: binary spikes (uint8), slabs ordered Qs,Qt,Ks,Vs,Kt,Vt.
// Per (t,b): out[2304x384] = Wstack[2304x384] @ in[384x384]
// ---------------------------------------------------------------------------
__global__ __launch_bounds__(256) void conv1_kernel(
    const float* __restrict__ x, const float* __restrict__ y,
    const float* __restrict__ sW, const float* __restrict__ sg, const float* __restrict__ sb,
    const float* __restrict__ tW, const float* __restrict__ tg, const float* __restrict__ tb,
    uint8_t* __restrict__ S1)
{
  const int ntile = blockIdx.x;      // 0..5
  const int mtile = blockIdx.y;      // 0..35  (6 convs x 6 row-tiles)
  const int tb_i  = blockIdx.z;      // 0..39  (t*4+b)
  const int conv = mtile / 6;
  const int oc0  = (mtile % 6) * 64;
  const int n0   = ntile * 64;

  const float* Wb; const float* g; const float* bsh; const float* in; int slot;
  switch (conv) {
    case 0:  Wb = sW;          g = sg; bsh = sb; in = x; slot = 0; break; // spatial q
    case 1:  Wb = tW;          g = tg; bsh = tb; in = x; slot = 0; break; // temporal q
    case 2:  Wb = sW + CN_;    g = sg; bsh = sb; in = y; slot = 1; break; // spatial k
    case 3:  Wb = sW + 2*CN_;  g = sg; bsh = sb; in = y; slot = 2; break; // spatial v
    case 4:  Wb = tW + CN_;    g = tg; bsh = tb; in = y; slot = 1; break; // temporal k
    default: Wb = tW + 2*CN_;  g = tg; bsh = tb; in = y; slot = 2; break; // temporal v
  }
  const float* inb = in + (size_t)tb_i * CN_;

  __shared__ float As[16][68];   // As[k][m] = W[oc0+m][k0+k]
  __shared__ float Bs[16][68];   // Bs[k][n] = in[k0+k][n0+n]
  float acc[4][4] = {};
  const int tid = threadIdx.x;
  const int tx = tid & 15, ty = tid >> 4;

  for (int k0 = 0; k0 < 384; k0 += 16) {
    {
      const int m = tid >> 2, kq = (tid & 3) * 4;
      const float4 w4 = *(const float4*)(Wb + (size_t)(oc0 + m) * 384 + k0 + kq);
      As[kq+0][m] = w4.x; As[kq+1][m] = w4.y; As[kq+2][m] = w4.z; As[kq+3][m] = w4.w;
    }
    {
      const int n = tid & 63, kr = tid >> 6;
      #pragma unroll
      for (int i = 0; i < 4; i++)
        Bs[kr + i*4][n] = inb[(size_t)(k0 + kr + i*4) * 384 + n0 + n];
    }
    __syncthreads();
    #pragma unroll
    for (int kk = 0; kk < 16; kk++) {
      float a[4], b4[4];
      #pragma unroll
      for (int i = 0; i < 4; i++) a[i] = As[kk][ty*4 + i];
      #pragma unroll
      for (int j = 0; j < 4; j++) b4[j] = Bs[kk][tx*4 + j];
      #pragma unroll
      for (int i = 0; i < 4; i++)
        #pragma unroll
        for (int j = 0; j < 4; j++)
          acc[i][j] = fmaf(a[i], b4[j], acc[i][j]);
    }
    __syncthreads();
  }

  uint8_t* out = S1 + (size_t)conv * TBCN_ + (size_t)tb_i * CN_;
  #pragma unroll
  for (int i = 0; i < 4; i++) {
    const int oc = oc0 + ty*4 + i;
    const float gg = g[slot*384 + oc], bb = bsh[slot*384 + oc];
    #pragma unroll
    for (int j = 0; j < 4; j++) {
      const int n = n0 + tx*4 + j;
      out[(size_t)oc * 384 + n] = (acc[i][j] * gg + bb >= 2.0f) ? 1 : 0;
    }
  }
}

// ---------------------------------------------------------------------------
// conv4: GEMM with binary (uint8) RHS + BN + LIF -> spikes. W/g/b pre-offset.
// ---------------------------------------------------------------------------
__global__ __launch_bounds__(256) void conv4_kernel(
    const uint8_t* __restrict__ Sin, const float* __restrict__ W,
    const float* __restrict__ g, const float* __restrict__ bsh,
    uint8_t* __restrict__ Sout)
{
  const int ntile = blockIdx.x;      // 0..5
  const int mtile = blockIdx.y;      // 0..5
  const int tb_i  = blockIdx.z;      // 0..39
  const int oc0 = mtile * 64, n0 = ntile * 64;
  const uint8_t* inb = Sin + (size_t)tb_i * CN_;

  __shared__ float As[16][68];
  __shared__ float Bs[16][68];
  float acc[4][4] = {};
  const int tid = threadIdx.x;
  const int tx = tid & 15, ty = tid >> 4;

  for (int k0 = 0; k0 < 384; k0 += 16) {
    {
      const int m = tid >> 2, kq = (tid & 3) * 4;
      const float4 w4 = *(const float4*)(W + (size_t)(oc0 + m) * 384 + k0 + kq);
      As[kq+0][m] = w4.x; As[kq+1][m] = w4.y; As[kq+2][m] = w4.z; As[kq+3][m] = w4.w;
    }
    {
      const int n = tid & 63, kr = tid >> 6;
      #pragma unroll
      for (int i = 0; i < 4; i++)
        Bs[kr + i*4][n] = (float)inb[(size_t)(k0 + kr + i*4) * 384 + n0 + n];
    }
    __syncthreads();
    #pragma unroll
    for (int kk = 0; kk < 16; kk++) {
      float a[4], b4[4];
      #pragma unroll
      for (int i = 0; i < 4; i++) a[i] = As[kk][ty*4 + i];
      #pragma unroll
      for (int j = 0; j < 4; j++) b4[j] = Bs[kk][tx*4 + j];
      #pragma unroll
      for (int i = 0; i < 4; i++)
        #pragma unroll
        for (int j = 0; j < 4; j++)
          acc[i][j] = fmaf(a[i], b4[j], acc[i][j]);
    }
    __syncthreads();
  }

  uint8_t* out = Sout + (size_t)tb_i * CN_;
  #pragma unroll
  for (int i = 0; i < 4; i++) {
    const int oc = oc0 + ty*4 + i;
    const float gg = g[oc], bb = bsh[oc];
    #pragma unroll
    for (int j = 0; j < 4; j++) {
      const int n = n0 + tx*4 + j;
      out[(size_t)oc * 384 + n] = (acc[i][j] * gg + bb >= 2.0f) ? 1 : 0;
    }
  }
}

// ---------------------------------------------------------------------------
// Spatial attention: per (t,b,h): o = q (k^T v), all binary -> exact ints.
// spike = (o >= 8)   [ o*SCALE/TAU >= V_TH ]
// ---------------------------------------------------------------------------
__global__ __launch_bounds__(256) void attn_spatial(
    const uint8_t* __restrict__ Qs, const uint8_t* __restrict__ Ks,
    const uint8_t* __restrict__ Vs, uint8_t* __restrict__ Osp)
{
  const int blk = blockIdx.x;                 // 0..479
  const int h = blk % 12, b = (blk / 12) % 4, t = blk / 48;
  const size_t base = (size_t)(t*4 + b) * CN_ + (size_t)h * 32 * 384;

  __shared__ uint32_t qb[384], kb[384], vb[384];
  __shared__ int ktv[32][33];
  const int tid = threadIdx.x;

  for (int n = tid; n < 384; n += 256) {
    uint32_t q = 0, k = 0, v = 0;
    #pragma unroll
    for (int j = 0; j < 32; j++) {
      q |= (uint32_t)Qs[base + (size_t)j*384 + n] << j;
      k |= (uint32_t)Ks[base + (size_t)j*384 + n] << j;
      v |= (uint32_t)Vs[base + (size_t)j*384 + n] << j;
    }
    qb[n] = q; kb[n] = k; vb[n] = v;
  }
  __syncthreads();

  {  // ktv[i][j] = sum_n k[n,i]*v[n,j]   (32x32, each thread does 4 entries)
    const int i = tid >> 3, j0 = (tid & 7) * 4;
    int s0 = 0, s1 = 0, s2 = 0, s3 = 0;
    for (int n = 0; n < 384; n++) {
      const uint32_t m = kb[n] >> i, vv = vb[n] >> j0;
      s0 += (m & vv) & 1;
      s1 += (m & (vv >> 1)) & 1;
      s2 += (m & (vv >> 2)) & 1;
      s3 += (m & (vv >> 3)) & 1;
    }
    ktv[i][j0] = s0; ktv[i][j0+1] = s1; ktv[i][j0+2] = s2; ktv[i][j0+3] = s3;
  }
  __syncthreads();

  uint8_t* outb = Osp + base;   // same (t,b,h) slab; channel c = h*32+dd
  for (int rep = 0; rep < 48; rep++) {
    const int idx = rep * 256 + tid;
    const int dd = idx / 384, n = idx % 384;
    const uint32_t q = qb[n];
    int o = 0;
    #pragma unroll
    for (int i = 0; i < 32; i++)
      o += ((q >> i) & 1) * ktv[i][dd];
    outb[(size_t)dd * 384 + n] = (o >= 8) ? 1 : 0;
  }
}

// ---------------------------------------------------------------------------
// Temporal attention: per (n,b,h): q,k,v are (10 x 32) bit-rows.
// attn = popcount(q&k), o = attn@v, spike=(o>=8); funky reshape on write:
// flat = h*320 + t*32 + dd -> t2 = flat/384, c2 = flat%384.
// ---------------------------------------------------------------------------
__global__ __launch_bounds__(64) void attn_temporal(
    const uint8_t* __restrict__ Qt, const uint8_t* __restrict__ Kt,
    const uint8_t* __restrict__ Vt, uint8_t* __restrict__ Otp)
{
  const int n = blockIdx.x * 64 + threadIdx.x;   // grid.x = 6
  const int h = blockIdx.y, b = blockIdx.z;

  uint32_t qb[10], kb[10], vb[10];
  #pragma unroll
  for (int t = 0; t < 10; t++) {
    const size_t base = ((size_t)(t*4 + b) * 384 + h*32) * 384 + n;
    uint32_t q = 0, k = 0, v = 0;
    #pragma unroll
    for (int j = 0; j < 32; j++) {
      q |= (uint32_t)Qt[base + (size_t)j*384] << j;
      k |= (uint32_t)Kt[base + (size_t)j*384] << j;
      v |= (uint32_t)Vt[base + (size_t)j*384] << j;
    }
    qb[t] = q; kb[t] = k; vb[t] = v;
  }

  #pragma unroll
  for (int t = 0; t < 10; t++) {
    int o[32];
    #pragma unroll
    for (int dd = 0; dd < 32; dd++) o[dd] = 0;
    #pragma unroll
    for (int s = 0; s < 10; s++) {
      const int a = __popc(qb[t] & kb[s]);
      const uint32_t v = vb[s];
      #pragma unroll
      for (int dd = 0; dd < 32; dd++)
        o[dd] += (int)((v >> dd) & 1) * a;
    }
    #pragma unroll
    for (int dd = 0; dd < 32; dd++) {
      const int flat = h*320 + t*32 + dd;
      const int t2 = flat / 384, c2 = flat % 384;
      Otp[((size_t)(t2*4 + b) * 384 + c2) * 384 + n] = (o[dd] >= 8) ? 1 : 0;
    }
  }
}

// ---------------------------------------------------------------------------
// reductions + final outer product
// ---------------------------------------------------------------------------
__global__ __launch_bounds__(256) void reduce_a(const uint8_t* __restrict__ a_spike,
                                                float* __restrict__ a_red)
{
  const int row = blockIdx.x * 4 + (threadIdx.x >> 6);   // (t,b,c) row, 15360 total
  const int lane = threadIdx.x & 63;
  const uint8_t* p = a_spike + (size_t)row * 384;
  int s = 0;
  #pragma unroll
  for (int i = 0; i < 6; i++) s += p[lane + i*64];
  #pragma unroll
  for (int off = 32; off; off >>= 1) s += __shfl_down(s, off, 64);
  if (lane == 0) a_red[row] = (float)s * (1.0f / 384.0f);
}

__global__ __launch_bounds__(256) void reduce_b(const uint8_t* __restrict__ bt_spike,
                                                float* __restrict__ b_red)
{
  const int idx = blockIdx.x * 256 + threadIdx.x;   // < 589824 (b,c,n)
  int s = 0;
  #pragma unroll
  for (int t = 0; t < 10; t++) s += bt_spike[(size_t)t * BCN_ + idx];
  b_red[idx] = (float)s * 0.1f;
}

__global__ __launch_bounds__(256) void final_kernel(const float* __restrict__ a_red,
                                                    const float* __restrict__ b_red,
                                                    float* __restrict__ out)
{
  const int idx = blockIdx.x * 256 + threadIdx.x;   // < 5898240
  out[idx] = a_red[idx / 384] * b_red[idx % BCN_];
}

// ---------------------------------------------------------------------------
extern "C" void kernel_launch(void* const* d_in, const int* in_sizes, int n_in,
                              void* d_out, int out_size, void* d_ws, size_t ws_size,
                              hipStream_t stream) {
  const float* x  = (const float*)d_in[0];
  const float* y  = (const float*)d_in[1];
  const float* sW = (const float*)d_in[2];
  const float* sg = (const float*)d_in[3];
  const float* sb = (const float*)d_in[4];
  const float* tW = (const float*)d_in[5];
  const float* tg = (const float*)d_in[6];
  const float* tb = (const float*)d_in[7];
  float* out = (float*)d_out;

  uint8_t* ws = (uint8_t*)d_ws;
  uint8_t* S1       = ws;                         // 6 slabs: Qs,Qt,Ks,Vs,Kt,Vt
  uint8_t* Osp      = ws + (size_t)6 * TBCN_;
  uint8_t* Otp      = Osp + TBCN_;
  uint8_t* a_spike  = Otp + TBCN_;
  uint8_t* bt_spike = a_spike + TBCN_;
  float*   a_red    = (float*)(bt_spike + TBCN_);
  float*   b_red    = a_red + 15360;

  uint8_t* Qs = S1;
  uint8_t* Qt = S1 + (size_t)1 * TBCN_;
  uint8_t* Ks = S1 + (size_t)2 * TBCN_;
  uint8_t* Vs = S1 + (size_t)3 * TBCN_;
  uint8_t* Kt = S1 + (size_t)4 * TBCN_;
  uint8_t* Vt = S1 + (size_t)5 * TBCN_;

  conv1_kernel<<<dim3(6, 36, 40), 256, 0, stream>>>(x, y, sW, sg, sb, tW, tg, tb, S1);

  attn_spatial<<<480, 256, 0, stream>>>(Qs, Ks, Vs, Osp);
  attn_temporal<<<dim3(6, 12, 4), 64, 0, stream>>>(Qt, Kt, Vt, Otp);

  conv4_kernel<<<dim3(6, 6, 40), 256, 0, stream>>>(Osp, sW + 3*CN_, sg + 3*384, sb + 3*384, a_spike);
  conv4_kernel<<<dim3(6, 6, 40), 256, 0, stream>>>(Otp, tW + 3*CN_, tg + 3*384, tb + 3*384, bt_spike);

  reduce_a<<<3840, 256, 0, stream>>>(a_spike, a_red);
  reduce_b<<<2304, 256, 0, stream>>>(bt_spike, b_red);
  final_kernel<<<23040, 256, 0, stream>>>(a_red, b_red, out);
}

// Round 2
// 688.833 us; speedup vs baseline: 1.0972x; 1.0972x over previous
//
#include <hip/hip_runtime.h>
#include <stdint.h>

#define T_ 10
#define B_ 4
#define C_ 384
#define N_ 384
#define H_ 12
#define CN_ 147456      // C_*N_
#define TBCN_ 5898240   // T_*B_*C_*N_
#define BCN_ 589824     // B_*C_*N_
#define PKN_ 184320     // 40*12*384  (packed words per q/k/v array)

// ---------------------------------------------------------------------------
// conv1: 6 first-layer convs (fp32 GEMM) + BN + LIF -> BIT-PACKED spikes.
// 128x128 tile, 8x8 per thread, BK=32. K-order sequential (bit-exact vs R1).
// Packed word: bit d (0..31) = spike of channel h*32+d at col n.
// Spatial layout: PS[(tb*12+h)*384 + n]; Temporal: PT[((b*12+h)*10+t)*384 + n].
// ---------------------------------------------------------------------------
__global__ __launch_bounds__(256) void conv1_kernel(
    const float* __restrict__ x, const float* __restrict__ y,
    const float* __restrict__ sW, const float* __restrict__ sg, const float* __restrict__ sb,
    const float* __restrict__ tW, const float* __restrict__ tg, const float* __restrict__ tb_,
    uint32_t* __restrict__ PSq, uint32_t* __restrict__ PSk, uint32_t* __restrict__ PSv,
    uint32_t* __restrict__ PTq, uint32_t* __restrict__ PTk, uint32_t* __restrict__ PTv)
{
  const int ntile = blockIdx.x;          // 0..2
  const int mt    = blockIdx.y;          // 0..17
  const int tb_i  = blockIdx.z;          // 0..39
  const int conv = mt / 3, row0 = (mt % 3) * 128;
  const int n0 = ntile * 128;
  const int t = tb_i >> 2, b = tb_i & 3;

  const float* Wb; const float* g; const float* bsh; const float* in;
  int slot; uint32_t* Pout; bool temporal;
  switch (conv) {
    case 0:  Wb = sW;         g = sg; bsh = sb;  in = x; slot = 0; Pout = PSq; temporal = false; break;
    case 1:  Wb = sW + CN_;   g = sg; bsh = sb;  in = y; slot = 1; Pout = PSk; temporal = false; break;
    case 2:  Wb = sW + 2*CN_; g = sg; bsh = sb;  in = y; slot = 2; Pout = PSv; temporal = false; break;
    case 3:  Wb = tW;         g = tg; bsh = tb_; in = x; slot = 0; Pout = PTq; temporal = true;  break;
    case 4:  Wb = tW + CN_;   g = tg; bsh = tb_; in = y; slot = 1; Pout = PTk; temporal = true;  break;
    default: Wb = tW + 2*CN_; g = tg; bsh = tb_; in = y; slot = 2; Pout = PTv; temporal = true;  break;
  }
  const float* inb = in + (size_t)tb_i * CN_;

  __shared__ float As[32][132];   // As[k][m] = W[row0+m][k0+k]
  __shared__ float Bs[32][132];   // Bs[k][n] = in[k0+k][n0+n]
  float acc[8][8] = {};
  const int tid = threadIdx.x;
  const int tx = tid & 15, ty = tid >> 4;
  const int r0 = ty * 8, c0a = tx * 4, c0b = 64 + tx * 4;

  const int am = tid >> 1, akq = (tid & 1) * 16;     // A-stage: 16 k per thread
  const int bk = tid >> 3, bc = (tid & 7) * 16;      // B-stage: 16 n per thread

  for (int k0 = 0; k0 < 384; k0 += 32) {
    #pragma unroll
    for (int q = 0; q < 4; q++) {
      const float4 w4 = *(const float4*)(Wb + (size_t)(row0 + am) * 384 + k0 + akq + q*4);
      As[akq + q*4 + 0][am] = w4.x; As[akq + q*4 + 1][am] = w4.y;
      As[akq + q*4 + 2][am] = w4.z; As[akq + q*4 + 3][am] = w4.w;
    }
    #pragma unroll
    for (int q = 0; q < 4; q++)
      *(float4*)&Bs[bk][bc + q*4] = *(const float4*)(inb + (size_t)(k0 + bk) * 384 + n0 + bc + q*4);
    __syncthreads();
    #pragma unroll
    for (int kk = 0; kk < 32; kk++) {
      float a[8], bv[8];
      *(float4*)&a[0]  = *(const float4*)&As[kk][r0];
      *(float4*)&a[4]  = *(const float4*)&As[kk][r0 + 4];
      *(float4*)&bv[0] = *(const float4*)&Bs[kk][c0a];
      *(float4*)&bv[4] = *(const float4*)&Bs[kk][c0b];
      #pragma unroll
      for (int i = 0; i < 8; i++)
        #pragma unroll
        for (int j = 0; j < 8; j++)
          acc[i][j] = fmaf(a[i], bv[j], acc[i][j]);
    }
    __syncthreads();
  }

  // BN + LIF + bit-pack (32 channels -> u32 via 2x shfl_xor across ty-groups)
  float gg[8], bb[8];
  #pragma unroll
  for (int i = 0; i < 8; i++) {
    const int oc = row0 + r0 + i;
    gg[i] = g[slot*384 + oc]; bb[i] = bsh[slot*384 + oc];
  }
  const int shift = (ty & 3) * 8;
  const int h = (row0 >> 5) + (ty >> 2);
  uint32_t words[8];
  #pragma unroll
  for (int j = 0; j < 8; j++) {
    uint32_t u = 0;
    #pragma unroll
    for (int i = 0; i < 8; i++)
      u |= (uint32_t)((acc[i][j] * gg[i] + bb[i] >= 2.0f) ? 1u : 0u) << i;
    uint32_t w = u << shift;
    w |= __shfl_xor(w, 16, 64);
    w |= __shfl_xor(w, 32, 64);
    words[j] = w;
  }
  if ((ty & 3) == 0) {
    const size_t base = temporal
        ? (((size_t)b * 12 + h) * 10 + t) * 384 + n0
        : ((size_t)tb_i * 12 + h) * 384 + n0;
    #pragma unroll
    for (int j = 0; j < 8; j++) {
      const int c = (j < 4) ? (c0a + j) : (c0b + j - 4);
      Pout[base + c] = words[j];
    }
  }
}

// ---------------------------------------------------------------------------
// conv4: fp32 GEMM with binary uint8 RHS + BN + LIF -> byte spikes.
// Same 128x128 structure. W/g/b pre-offset by caller.
// ---------------------------------------------------------------------------
__global__ __launch_bounds__(256) void conv4_kernel(
    const uint8_t* __restrict__ Sin, const float* __restrict__ W,
    const float* __restrict__ g, const float* __restrict__ bsh,
    uint8_t* __restrict__ Sout)
{
  const int ntile = blockIdx.x;      // 0..2
  const int mtile = blockIdx.y;      // 0..2
  const int tb_i  = blockIdx.z;      // 0..39
  const int row0 = mtile * 128, n0 = ntile * 128;
  const uint8_t* inb = Sin + (size_t)tb_i * CN_;

  __shared__ float As[32][132];
  __shared__ float Bs[32][132];
  float acc[8][8] = {};
  const int tid = threadIdx.x;
  const int tx = tid & 15, ty = tid >> 4;
  const int r0 = ty * 8, c0a = tx * 4, c0b = 64 + tx * 4;
  const int am = tid >> 1, akq = (tid & 1) * 16;
  const int bk = tid >> 3, bc = (tid & 7) * 16;

  for (int k0 = 0; k0 < 384; k0 += 32) {
    #pragma unroll
    for (int q = 0; q < 4; q++) {
      const float4 w4 = *(const float4*)(W + (size_t)(row0 + am) * 384 + k0 + akq + q*4);
      As[akq + q*4 + 0][am] = w4.x; As[akq + q*4 + 1][am] = w4.y;
      As[akq + q*4 + 2][am] = w4.z; As[akq + q*4 + 3][am] = w4.w;
    }
    {
      const uint4 u = *(const uint4*)(inb + (size_t)(k0 + bk) * 384 + n0 + bc);
      const uint32_t wd[4] = {u.x, u.y, u.z, u.w};
      #pragma unroll
      for (int q = 0; q < 4; q++) {
        float4 f;
        f.x = (float)( wd[q]        & 0xff);
        f.y = (float)((wd[q] >> 8)  & 0xff);
        f.z = (float)((wd[q] >> 16) & 0xff);
        f.w = (float)((wd[q] >> 24) & 0xff);
        *(float4*)&Bs[bk][bc + q*4] = f;
      }
    }
    __syncthreads();
    #pragma unroll
    for (int kk = 0; kk < 32; kk++) {
      float a[8], bv[8];
      *(float4*)&a[0]  = *(const float4*)&As[kk][r0];
      *(float4*)&a[4]  = *(const float4*)&As[kk][r0 + 4];
      *(float4*)&bv[0] = *(const float4*)&Bs[kk][c0a];
      *(float4*)&bv[4] = *(const float4*)&Bs[kk][c0b];
      #pragma unroll
      for (int i = 0; i < 8; i++)
        #pragma unroll
        for (int j = 0; j < 8; j++)
          acc[i][j] = fmaf(a[i], bv[j], acc[i][j]);
    }
    __syncthreads();
  }

  uint8_t* outb = Sout + (size_t)tb_i * CN_;
  #pragma unroll
  for (int i = 0; i < 8; i++) {
    const int oc = row0 + r0 + i;
    const float ggv = g[oc], bbv = bsh[oc];
    uint32_t pa = 0, pb = 0;
    #pragma unroll
    for (int j = 0; j < 4; j++) {
      pa |= (uint32_t)((acc[i][j]     * ggv + bbv >= 2.0f) ? 1u : 0u) << (8*j);
      pb |= (uint32_t)((acc[i][j + 4] * ggv + bbv >= 2.0f) ? 1u : 0u) << (8*j);
    }
    *(uint32_t*)(outb + (size_t)oc * 384 + n0 + c0a) = pa;
    *(uint32_t*)(outb + (size_t)oc * 384 + n0 + c0b) = pb;
  }
}

// ---------------------------------------------------------------------------
// Spatial attention: per (t,b,h): o = q (k^T v), exact ints; spike=(o>=8).
// Inputs bit-packed; output byte spikes for conv4.
// ---------------------------------------------------------------------------
__global__ __launch_bounds__(256) void attn_spatial(
    const uint32_t* __restrict__ PSq, const uint32_t* __restrict__ PSk,
    const uint32_t* __restrict__ PSv, uint8_t* __restrict__ Osp)
{
  const int blk = blockIdx.x;                 // 0..479
  const int h = blk % 12, tb_i = blk / 12;
  const size_t pbase = ((size_t)tb_i * 12 + h) * 384;

  __shared__ uint32_t qb[384], kb[384], vb[384];
  __shared__ int ktv[32][33];
  const int tid = threadIdx.x;

  for (int n = tid; n < 384; n += 256) {
    qb[n] = PSq[pbase + n]; kb[n] = PSk[pbase + n]; vb[n] = PSv[pbase + n];
  }
  __syncthreads();

  {  // ktv[i][j] = sum_n k[n,i]*v[n,j]
    const int i = tid >> 3, j0 = (tid & 7) * 4;
    int s0 = 0, s1 = 0, s2 = 0, s3 = 0;
    for (int n = 0; n < 384; n++) {
      const uint32_t m = kb[n] >> i, vv = vb[n] >> j0;
      s0 += (m & vv) & 1;
      s1 += (m & (vv >> 1)) & 1;
      s2 += (m & (vv >> 2)) & 1;
      s3 += (m & (vv >> 3)) & 1;
    }
    ktv[i][j0] = s0; ktv[i][j0+1] = s1; ktv[i][j0+2] = s2; ktv[i][j0+3] = s3;
  }
  __syncthreads();

  uint8_t* outb = Osp + (size_t)tb_i * CN_ + (size_t)h * 32 * 384;
  for (int rep = 0; rep < 48; rep++) {
    const int idx = rep * 256 + tid;
    const int dd = idx / 384, n = idx % 384;
    const uint32_t q = qb[n];
    int o = 0;
    #pragma unroll
    for (int i = 0; i < 32; i++)
      o += ((q >> i) & 1) * ktv[i][dd];
    outb[(size_t)dd * 384 + n] = (o >= 8) ? 1 : 0;
  }
}

// ---------------------------------------------------------------------------
// Temporal attention: per (n,b,h): attn = popcount(q&k) (10x10), o = attn@v.
// flat = h*320 + t*32 + dd -> t2 = flat/384, c2 = flat%384 (torch reshape).
// ---------------------------------------------------------------------------
__global__ __launch_bounds__(384) void attn_temporal(
    const uint32_t* __restrict__ PTq, const uint32_t* __restrict__ PTk,
    const uint32_t* __restrict__ PTv, uint8_t* __restrict__ Otp)
{
  const int n = threadIdx.x;                  // 0..383
  const int h = blockIdx.x, b = blockIdx.y;
  const size_t base = (((size_t)b * 12 + h) * 10) * 384 + n;

  uint32_t qb[10], kb[10], vb[10];
  #pragma unroll
  for (int t = 0; t < 10; t++) {
    qb[t] = PTq[base + (size_t)t * 384];
    kb[t] = PTk[base + (size_t)t * 384];
    vb[t] = PTv[base + (size_t)t * 384];
  }

  #pragma unroll
  for (int t = 0; t < 10; t++) {
    int o[32];
    #pragma unroll
    for (int dd = 0; dd < 32; dd++) o[dd] = 0;
    #pragma unroll
    for (int s = 0; s < 10; s++) {
      const int a = __popc(qb[t] & kb[s]);
      const uint32_t v = vb[s];
      #pragma unroll
      for (int dd = 0; dd < 32; dd++)
        o[dd] += (int)((v >> dd) & 1) * a;
    }
    #pragma unroll
    for (int dd = 0; dd < 32; dd++) {
      const int flat = h*320 + t*32 + dd;
      const int t2 = flat / 384, c2 = flat % 384;
      Otp[((size_t)(t2*4 + b) * 384 + c2) * 384 + n] = (o[dd] >= 8) ? 1 : 0;
    }
  }
}

// ---------------------------------------------------------------------------
// reductions + final outer product
// ---------------------------------------------------------------------------
__global__ __launch_bounds__(256) void reduce_a(const uint8_t* __restrict__ a_spike,
                                                float* __restrict__ a_red)
{
  const int row = blockIdx.x * 4 + (threadIdx.x >> 6);   // (t,b,c) row, 15360 total
  const int lane = threadIdx.x & 63;
  const uint8_t* p = a_spike + (size_t)row * 384;
  int s = 0;
  #pragma unroll
  for (int i = 0; i < 6; i++) s += p[lane + i*64];
  #pragma unroll
  for (int off = 32; off; off >>= 1) s += __shfl_down(s, off, 64);
  if (lane == 0) a_red[row] = (float)s * (1.0f / 384.0f);
}

__global__ __launch_bounds__(256) void reduce_b(const uint8_t* __restrict__ bt_spike,
                                                float* __restrict__ b_red)
{
  const int idx = blockIdx.x * 256 + threadIdx.x;   // < 589824 (b,c,n)
  int s = 0;
  #pragma unroll
  for (int t = 0; t < 10; t++) s += bt_spike[(size_t)t * BCN_ + idx];
  b_red[idx] = (float)s * 0.1f;
}

__global__ __launch_bounds__(256) void final_kernel(const float* __restrict__ a_red,
                                                    const float* __restrict__ b_red,
                                                    float* __restrict__ out)
{
  const int idx = blockIdx.x * 256 + threadIdx.x;   // < 5898240
  out[idx] = a_red[idx / 384] * b_red[idx % BCN_];
}

// ---------------------------------------------------------------------------
extern "C" void kernel_launch(void* const* d_in, const int* in_sizes, int n_in,
                              void* d_out, int out_size, void* d_ws, size_t ws_size,
                              hipStream_t stream) {
  const float* x  = (const float*)d_in[0];
  const float* y  = (const float*)d_in[1];
  const float* sW = (const float*)d_in[2];
  const float* sg = (const float*)d_in[3];
  const float* sb = (const float*)d_in[4];
  const float* tW = (const float*)d_in[5];
  const float* tg = (const float*)d_in[6];
  const float* tb = (const float*)d_in[7];
  float* out = (float*)d_out;

  uint32_t* PSq = (uint32_t*)d_ws;
  uint32_t* PSk = PSq + PKN_;
  uint32_t* PSv = PSk + PKN_;
  uint32_t* PTq = PSv + PKN_;
  uint32_t* PTk = PTq + PKN_;
  uint32_t* PTv = PTk + PKN_;
  float* a_red = (float*)(PTv + PKN_);
  float* b_red = a_red + 15360;
  uint8_t* Osp      = (uint8_t*)(b_red + BCN_);
  uint8_t* Otp      = Osp + TBCN_;
  uint8_t* a_spike  = Otp + TBCN_;
  uint8_t* bt_spike = a_spike + TBCN_;

  conv1_kernel<<<dim3(3, 18, 40), 256, 0, stream>>>(x, y, sW, sg, sb, tW, tg, tb,
                                                    PSq, PSk, PSv, PTq, PTk, PTv);

  attn_spatial<<<480, 256, 0, stream>>>(PSq, PSk, PSv, Osp);
  attn_temporal<<<dim3(12, 4), 384, 0, stream>>>(PTq, PTk, PTv, Otp);

  conv4_kernel<<<dim3(3, 3, 40), 256, 0, stream>>>(Osp, sW + 3*CN_, sg + 3*384, sb + 3*384, a_spike);
  conv4_kernel<<<dim3(3, 3, 40), 256, 0, stream>>>(Otp, tW + 3*CN_, tg + 3*384, tb + 3*384, bt_spike);

  reduce_a<<<3840, 256, 0, stream>>>(a_spike, a_red);
  reduce_b<<<2304, 256, 0, stream>>>(bt_spike, b_red);
  final_kernel<<<23040, 256, 0, stream>>>(a_red, b_red, out);
}